// Round 13
// baseline (278.331 us; speedup 1.0000x reference)
//
#include <hip/hip_runtime.h>
#include <hip/hip_bf16.h>
#include <math.h>

// ---------------------------------------------------------------------------
// GAT x2 + folded (v-proj -> out-proj -> fc) + log_softmax
//   CSR build: bucket-binning (128-node buckets), esrc uint16. TILE=2048 for
//     bin kernels (4x blocks -- latency-bound atomic loops need waves).
//   gemm1: MFMA bf16 16x16x32, 64x64 tile.
//   gat_agg64_g2: 1 node/wave, quad layout x4 + esrc prefetch; fused gemm2.
//     LDS staging writes linearized (R11: staging stride caused 2.4M
//     write conflicts, not the reads).
//   gat_agg32_fin: 1 node/wave, unmasked 32-stride main + masked 8-stride
//     tail; fused final matvec + log_softmax.
//   Lessons: independent gather streams >> fewer VALU instrs (R6/R8);
//   __shfl = DS op, avoid in epilogues (R7); LDS 4l%32 stride aliases, write
//   side too (R9/R11); many short blocks >> few long blocks (R10/R12).
// ---------------------------------------------------------------------------

#define BSHIFT 7
#define BMASK  ((1 << BSHIFT) - 1)
#define MAXNB  512
#define TILE   2048
#define XST    136

typedef __attribute__((ext_vector_type(8))) short short8;
typedef __attribute__((ext_vector_type(4))) float floatx4;

__device__ __forceinline__ unsigned short f2bf(float f) {
    union { float f; unsigned int u; } v; v.f = f;
    unsigned int u = v.u;
    return (unsigned short)((u + 0x7FFFu + ((u >> 16) & 1u)) >> 16);  // RNE
}
__device__ __forceinline__ float bfl2f(unsigned int p) {
    return __uint_as_float(p << 16);
}
__device__ __forceinline__ float bfh2f(unsigned int p) {
    return __uint_as_float(p & 0xFFFF0000u);
}
__device__ __forceinline__ float lrelu(float e) { return fmaxf(e, 0.2f * e); }
__device__ __forceinline__ float elu(float o) {
    return (o > 0.f) ? o : (__expf(o) - 1.f);
}

// ---------------- CSR build (bucket binning) ----------------
__global__ __launch_bounds__(256) void bin_count_kernel(
    const int* __restrict__ ei, int E, int Et, int NB,
    int* __restrict__ bcount) {
    __shared__ int h[MAXNB];
    for (int i = threadIdx.x; i < NB; i += 256) h[i] = 0;
    __syncthreads();
    int tile0 = blockIdx.x * TILE;
    int jend = tile0 + TILE; if (jend > Et) jend = Et;
    for (int j = tile0 + threadIdx.x; j < jend; j += 256) {
        int d = (j < E) ? ei[E + j] : (j - E);
        atomicAdd(&h[d >> BSHIFT], 1);
    }
    __syncthreads();
    for (int i = threadIdx.x; i < NB; i += 256)
        if (h[i]) atomicAdd(&bcount[i], h[i]);
}

__global__ __launch_bounds__(512) void bucket_scan_kernel(
    const int* __restrict__ bcount, int* __restrict__ bbase,
    int* __restrict__ gcur, int NB) {
    __shared__ int s[512];
    int t = threadIdx.x;
    int v = (t < NB) ? bcount[t] : 0;
    s[t] = v;
    __syncthreads();
    for (int off = 1; off < 512; off <<= 1) {
        int u = (t >= off) ? s[t - off] : 0;
        __syncthreads();
        s[t] += u;
        __syncthreads();
    }
    if (t < NB) { int b = s[t] - v; bbase[t] = b; gcur[t] = b; }
}

__global__ __launch_bounds__(256) void bin_scatter_kernel(
    const int* __restrict__ ei, int E, int Et, int NB,
    int* __restrict__ gcur, unsigned int* __restrict__ rec) {
    __shared__ int h[MAXNB];
    __shared__ int cur[MAXNB];
    for (int i = threadIdx.x; i < NB; i += 256) h[i] = 0;
    __syncthreads();
    int tile0 = blockIdx.x * TILE;
    int jend = tile0 + TILE; if (jend > Et) jend = Et;
    for (int j = tile0 + threadIdx.x; j < jend; j += 256) {
        int d = (j < E) ? ei[E + j] : (j - E);
        atomicAdd(&h[d >> BSHIFT], 1);
    }
    __syncthreads();
    for (int i = threadIdx.x; i < NB; i += 256)
        cur[i] = atomicAdd(&gcur[i], h[i]);
    __syncthreads();
    for (int j = tile0 + threadIdx.x; j < jend; j += 256) {
        int srcv, d;
        if (j < E) { srcv = ei[j]; d = ei[E + j]; } else { srcv = j - E; d = j - E; }
        int b = d >> BSHIFT;
        int pos = atomicAdd(&cur[b], 1);
        rec[pos] = (unsigned)srcv | ((unsigned)(d & BMASK) << 16);
    }
}

__global__ __launch_bounds__(256) void csr_finalize_kernel(
    const unsigned int* __restrict__ rec, const int* __restrict__ bcount,
    const int* __restrict__ bbase, int* __restrict__ rowp,
    unsigned short* __restrict__ esrc, int N, int Et) {
    __shared__ int h[128];
    __shared__ int nb[128];
    __shared__ int cur[128];
    int b = blockIdx.x, t = threadIdx.x;
    int base = bbase[b], cnt = bcount[b];
    if (t < 128) h[t] = 0;
    __syncthreads();
    for (int i = t; i < cnt; i += 256)
        atomicAdd(&h[(rec[base + i] >> 16) & 127], 1);
    __syncthreads();
    if (t == 0) {
        int run = base;
        for (int i = 0; i < 128; ++i) { nb[i] = run; run += h[i]; }
    }
    __syncthreads();
    if (t < 128) cur[t] = nb[t];
    int n0 = b << BSHIFT;
    if (t < 128 && n0 + t < N) rowp[n0 + t] = nb[t];
    if (b == 0 && t == 0) rowp[N] = Et;
    __syncthreads();
    for (int i = t; i < cnt; i += 256) {
        unsigned r = rec[base + i];
        int pos = atomicAdd(&cur[(r >> 16) & 127], 1);
        esrc[pos] = (unsigned short)(r & 0xFFFFu);
    }
}

// ---------------- gemm1 via MFMA ----------------
__global__ __launch_bounds__(256) void gemm1_mfma_kernel(
    const float* __restrict__ x, const float* __restrict__ W,
    const float* __restrict__ a_src, const float* __restrict__ a_dst,
    __hip_bfloat16* __restrict__ h, float* __restrict__ als,
    float* __restrict__ ald, int N) {
    __shared__ __align__(16) unsigned short xs[64 * XST];
    __shared__ __align__(16) unsigned short wt[64 * XST];
    int t = threadIdx.x;
    int nb = blockIdx.x * 64;
#pragma unroll
    for (int r = 0; r < 8; ++r) {
        int p = t + 256 * r;
        int row = p >> 5;
        int c4  = p & 31;
        int n = nb + row;
        float4 v = (n < N) ? ((const float4*)x)[(size_t)n * 32 + c4]
                           : make_float4(0.f, 0.f, 0.f, 0.f);
        unsigned short* dst = &xs[row * XST + c4 * 4];
        dst[0] = f2bf(v.x); dst[1] = f2bf(v.y);
        dst[2] = f2bf(v.z); dst[3] = f2bf(v.w);
    }
    {
        int n = t & 63, kg = t >> 6;
#pragma unroll
        for (int c = 0; c < 4; ++c) {
            int k0 = kg * 32 + c * 8;
            unsigned short* dst = &wt[n * XST + k0];
#pragma unroll
            for (int j = 0; j < 8; ++j)
                dst[j] = f2bf(W[(k0 + j) * 64 + n]);
        }
    }
    __syncthreads();
    int wave = t >> 6, lane = t & 63;
    int m16 = lane & 15, quad = lane >> 4;
    floatx4 acc[4];
#pragma unroll
    for (int i = 0; i < 4; ++i) acc[i] = (floatx4){0.f, 0.f, 0.f, 0.f};
#pragma unroll
    for (int k = 0; k < 4; ++k) {
        int koff = k * 32 + quad * 8;
        short8 afrag = *(const short8*)&xs[(wave * 16 + m16) * XST + koff];
#pragma unroll
        for (int nt = 0; nt < 4; ++nt) {
            short8 bfrag = *(const short8*)&wt[(nt * 16 + m16) * XST + koff];
            acc[nt] = __builtin_amdgcn_mfma_f32_16x16x32_bf16(afrag, bfrag, acc[nt], 0, 0, 0);
        }
    }
    __syncthreads();
    float* hs = (float*)xs;                // [64][65]
#pragma unroll
    for (int nt = 0; nt < 4; ++nt)
#pragma unroll
        for (int r = 0; r < 4; ++r)
            hs[(wave * 16 + quad * 4 + r) * 65 + nt * 16 + m16] = acc[nt][r];
    __syncthreads();
    float asv = a_src[lane], adv = a_dst[lane];
    for (int itn = 0; itn < 16; ++itn) {
        int nl = wave * 16 + itn;
        int n = nb + nl;
        if (n >= N) break;
        float v = hs[nl * 65 + lane];
        h[(size_t)n * 64 + lane] = __float2bfloat16(v);
        float ps = v * asv, pd = v * adv;
        ps += __shfl_xor(ps, 1); ps += __shfl_xor(ps, 2); ps += __shfl_xor(ps, 4);
        pd += __shfl_xor(pd, 1); pd += __shfl_xor(pd, 2); pd += __shfl_xor(pd, 4);
        if ((lane & 7) == 0) {
            als[n * 8 + (lane >> 3)] = ps;
            ald[n * 8 + (lane >> 3)] = pd;
        }
    }
}

// ---------------- agg layer 1 (quad x4 + prefetch) + fused gemm2 ----------
// One wave per node (4 nodes/block). W2p[kh][g][l][4]; staging LINEARIZED:
// consecutive threads write consecutive LDS addresses (no write conflicts).
__global__ __launch_bounds__(256) void gat_agg64_g2_kernel(
    const int* __restrict__ rowp, const unsigned short* __restrict__ esrc,
    const __hip_bfloat16* __restrict__ feat, const float* __restrict__ als,
    const float* __restrict__ ald_arr, const float* __restrict__ bias,
    const float* __restrict__ W2, const float* __restrict__ a2s,
    const float* __restrict__ a2d,
    __hip_bfloat16* __restrict__ h2out, float* __restrict__ als2,
    float* __restrict__ ald2, int N) {
    __shared__ __align__(16) float W2p[2][8][32][4];  // [kh][g][l][jj]
    __shared__ __align__(16) float oL[4][64];
    int t = threadIdx.x;
    {
        float* W2f = &W2p[0][0][0][0];
        for (int d = t; d < 2048; d += 256) {
            int jj = d & 3, l = (d >> 2) & 31, g = (d >> 7) & 7, kh = d >> 10;
            W2f[d] = W2[(kh * 32 + g * 4 + jj) * 32 + l];
        }
    }
    __syncthreads();
    const int lane = t & 63;
    const int wv = t >> 6;
    const int e = lane >> 4;             // edge slot 0..3
    const int c = lane & 15;             // channel quad
    const int hd = c >> 1;               // head
    int n = blockIdx.x * 4 + wv;
    if (n >= N) return;
    float aldv = ald_arr[n * 8 + hd];
    int beg = rowp[n], end = rowp[n + 1];
    float dA = 0.f, dB = 0.f;
    float p00 = 0.f, p01 = 0.f, p02 = 0.f, p03 = 0.f;
    float p10 = 0.f, p11 = 0.f, p12 = 0.f, p13 = 0.f;
    float p20 = 0.f, p21 = 0.f, p22 = 0.f, p23 = 0.f;
    float p30 = 0.f, p31 = 0.f, p32 = 0.f, p33 = 0.f;
    const uint2* fp = (const uint2*)feat;    // 16 8B-granules per row
    int i = beg;
    int s0, s1, s2, s3;
    bool has = (i + 16 <= end);
    if (has) {
        s0 = esrc[i + e]; s1 = esrc[i + 4 + e];
        s2 = esrc[i + 8 + e]; s3 = esrc[i + 12 + e];
    }
    while (has) {
        int t0 = s0, t1 = s1, t2 = s2, t3 = s3;
        i += 16;
        has = (i + 16 <= end);
        if (has) {                        // prefetch next group
            s0 = esrc[i + e]; s1 = esrc[i + 4 + e];
            s2 = esrc[i + 8 + e]; s3 = esrc[i + 12 + e];
        }
        float e0 = als[t0 * 8 + hd] + aldv;
        float e1 = als[t1 * 8 + hd] + aldv;
        float e2 = als[t2 * 8 + hd] + aldv;
        float e3 = als[t3 * 8 + hd] + aldv;
        uint2 g0 = fp[t0 * 16 + c];
        uint2 g1 = fp[t1 * 16 + c];
        uint2 g2 = fp[t2 * 16 + c];
        uint2 g3 = fp[t3 * 16 + c];
        float w0 = __expf(lrelu(e0));
        float w1 = __expf(lrelu(e1));
        float w2 = __expf(lrelu(e2));
        float w3 = __expf(lrelu(e3));
        dA += w0; dB += w1; dA += w2; dB += w3;
        p00 += w0 * bfl2f(g0.x); p01 += w0 * bfh2f(g0.x);
        p02 += w0 * bfl2f(g0.y); p03 += w0 * bfh2f(g0.y);
        p10 += w1 * bfl2f(g1.x); p11 += w1 * bfh2f(g1.x);
        p12 += w1 * bfl2f(g1.y); p13 += w1 * bfh2f(g1.y);
        p20 += w2 * bfl2f(g2.x); p21 += w2 * bfh2f(g2.x);
        p22 += w2 * bfl2f(g2.y); p23 += w2 * bfh2f(g2.y);
        p30 += w3 * bfl2f(g3.x); p31 += w3 * bfh2f(g3.x);
        p32 += w3 * bfl2f(g3.y); p33 += w3 * bfh2f(g3.y);
    }
    for (; i < end; i += 4) {            // masked tail, 4 at a time
        int rem = end - i;
        int ee = (e < rem) ? e : rem - 1;
        int s = esrc[i + ee];
        float ev = als[s * 8 + hd] + aldv;
        uint2 g = fp[s * 16 + c];
        float w = (e < rem) ? __expf(lrelu(ev)) : 0.f;
        dA += w;
        p00 += w * bfl2f(g.x); p01 += w * bfh2f(g.x);
        p02 += w * bfl2f(g.y); p03 += w * bfh2f(g.y);
    }
    float d = dA + dB;
    float P0 = (p00 + p10) + (p20 + p30);
    float P1 = (p01 + p11) + (p21 + p31);
    float P2 = (p02 + p12) + (p22 + p32);
    float P3 = (p03 + p13) + (p23 + p33);
    d  += __shfl_xor(d, 16);  d  += __shfl_xor(d, 32);
    P0 += __shfl_xor(P0, 16); P0 += __shfl_xor(P0, 32);
    P1 += __shfl_xor(P1, 16); P1 += __shfl_xor(P1, 32);
    P2 += __shfl_xor(P2, 16); P2 += __shfl_xor(P2, 32);
    P3 += __shfl_xor(P3, 16); P3 += __shfl_xor(P3, 32);
    float inv = 1.f / (d + 1e-16f);
    float4 bv = ((const float4*)bias)[c];
    float o0 = elu(P0 * inv + bv.x);
    float o1 = elu(P1 * inv + bv.y);
    float o2 = elu(P2 * inv + bv.z);
    float o3 = elu(P3 * inv + bv.w);
    if (lane < 16) *(float4*)&oL[wv][c * 4] = make_float4(o0, o1, o2, o3);
    // gemm2: h2[l] = sum_k o[k]*W2[k][l]; split-k over wave halves
    const int l = lane & 31, kh = lane >> 5;
    const float* orow = &oL[wv][kh * 32];
    float a0 = 0.f, a1 = 0.f, a2 = 0.f, a3 = 0.f;
#pragma unroll
    for (int g = 0; g < 8; ++g) {
        float4 ov = *(const float4*)&orow[g * 4];
        float4 wv4 = *(const float4*)&W2p[kh][g][l][0];
        a0 += ov.x * wv4.x; a1 += ov.y * wv4.y;
        a2 += ov.z * wv4.z; a3 += ov.w * wv4.w;
    }
    float acc = (a0 + a1) + (a2 + a3);
    acc += __shfl_xor(acc, 32);
    float ps = acc * a2s[l], pd = acc * a2d[l];
    ps += __shfl_xor(ps, 1); ps += __shfl_xor(ps, 2);
    pd += __shfl_xor(pd, 1); pd += __shfl_xor(pd, 2);
    if (lane < 32) {
        h2out[(size_t)n * 32 + l] = __float2bfloat16(acc);
        if ((l & 3) == 0) {
            als2[n * 8 + (l >> 2)] = ps;
            ald2[n * 8 + (l >> 2)] = pd;
        }
    }
}

// ---------------- agg layer 2 (octo) + fused final ----------
// One wave per node (4 nodes/block). lane = e*8 + c. Unmasked 32-stride main
// loop (4 streams) + masked 8-stride tail. Mp staged linearized.
__global__ __launch_bounds__(256) void gat_agg32_fin_kernel(
    const int* __restrict__ rowp, const unsigned short* __restrict__ esrc,
    const __hip_bfloat16* __restrict__ feat, const float* __restrict__ als,
    const float* __restrict__ ald_arr, const float* __restrict__ bias,
    const float* __restrict__ M, const float* __restrict__ bf,
    float* __restrict__ out, int N) {
    __shared__ __align__(16) float Mp[8][16][4];   // [g][j][jj]
    __shared__ float bfs[16];
    __shared__ __align__(16) float oL[4][32];
    int t = threadIdx.x;
    {
        float* Mpf = &Mp[0][0][0];
        for (int d = t; d < 512; d += 256) {
            int jj = d & 3, j = (d >> 2) & 15, g = d >> 6;
            Mpf[d] = M[j * 32 + g * 4 + jj];
        }
    }
    if (t < 16) bfs[t] = bf[t];
    __syncthreads();
    const int lane = t & 63;
    const int wv = t >> 6;
    const int e = lane >> 3;             // edge slot 0..7
    const int c = lane & 7;              // head, channels 4c..4c+3
    int n = blockIdx.x * 4 + wv;
    if (n >= N) return;
    float aldv = ald_arr[n * 8 + c];
    int beg = rowp[n], end = rowp[n + 1];
    float d0 = 0.f, d1 = 0.f, d2 = 0.f, d3 = 0.f;
    float p00 = 0.f, p01 = 0.f, p02 = 0.f, p03 = 0.f;
    float p10 = 0.f, p11 = 0.f, p12 = 0.f, p13 = 0.f;
    float p20 = 0.f, p21 = 0.f, p22 = 0.f, p23 = 0.f;
    float p30 = 0.f, p31 = 0.f, p32 = 0.f, p33 = 0.f;
    const uint2* fp = (const uint2*)feat;    // 8 granules per row
    int i = beg;
    for (; i + 32 <= end; i += 32) {     // unmasked main, 4 streams
        int s0 = esrc[i + e];
        int s1 = esrc[i + 8 + e];
        int s2 = esrc[i + 16 + e];
        int s3 = esrc[i + 24 + e];
        float e0 = als[s0 * 8 + c] + aldv;
        float e1 = als[s1 * 8 + c] + aldv;
        float e2 = als[s2 * 8 + c] + aldv;
        float e3 = als[s3 * 8 + c] + aldv;
        uint2 g0 = fp[s0 * 8 + c];
        uint2 g1 = fp[s1 * 8 + c];
        uint2 g2 = fp[s2 * 8 + c];
        uint2 g3 = fp[s3 * 8 + c];
        float w0 = __expf(lrelu(e0));
        float w1 = __expf(lrelu(e1));
        float w2 = __expf(lrelu(e2));
        float w3 = __expf(lrelu(e3));
        d0 += w0; d1 += w1; d2 += w2; d3 += w3;
        p00 += w0 * bfl2f(g0.x); p01 += w0 * bfh2f(g0.x);
        p02 += w0 * bfl2f(g0.y); p03 += w0 * bfh2f(g0.y);
        p10 += w1 * bfl2f(g1.x); p11 += w1 * bfh2f(g1.x);
        p12 += w1 * bfl2f(g1.y); p13 += w1 * bfh2f(g1.y);
        p20 += w2 * bfl2f(g2.x); p21 += w2 * bfh2f(g2.x);
        p22 += w2 * bfl2f(g2.y); p23 += w2 * bfh2f(g2.y);
        p30 += w3 * bfl2f(g3.x); p31 += w3 * bfh2f(g3.x);
        p32 += w3 * bfl2f(g3.y); p33 += w3 * bfh2f(g3.y);
    }
    for (; i < end; i += 8) {            // masked tail, 8 at a time
        int rem = end - i;
        int ee = (e < rem) ? e : rem - 1;
        int s = esrc[i + ee];
        float ev = als[s * 8 + c] + aldv;
        uint2 g = fp[s * 8 + c];
        float w = (e < rem) ? __expf(lrelu(ev)) : 0.f;
        d0 += w;
        p00 += w * bfl2f(g.x); p01 += w * bfh2f(g.x);
        p02 += w * bfl2f(g.y); p03 += w * bfh2f(g.y);
    }
    float d = (d0 + d1) + (d2 + d3);
    float P0 = (p00 + p10) + (p20 + p30);
    float P1 = (p01 + p11) + (p21 + p31);
    float P2 = (p02 + p12) + (p22 + p32);
    float P3 = (p03 + p13) + (p23 + p33);
    d  += __shfl_xor(d, 8);  d  += __shfl_xor(d, 16);  d  += __shfl_xor(d, 32);
    P0 += __shfl_xor(P0, 8); P0 += __shfl_xor(P0, 16); P0 += __shfl_xor(P0, 32);
    P1 += __shfl_xor(P1, 8); P1 += __shfl_xor(P1, 16); P1 += __shfl_xor(P1, 32);
    P2 += __shfl_xor(P2, 8); P2 += __shfl_xor(P2, 16); P2 += __shfl_xor(P2, 32);
    P3 += __shfl_xor(P3, 8); P3 += __shfl_xor(P3, 16); P3 += __shfl_xor(P3, 32);
    float inv = 1.f / (d + 1e-16f);
    float4 bv = ((const float4*)bias)[c];
    float o0 = elu(P0 * inv + bv.x);
    float o1 = elu(P1 * inv + bv.y);
    float o2 = elu(P2 * inv + bv.z);
    float o3 = elu(P3 * inv + bv.w);
    if (lane < 8) *(float4*)&oL[wv][c * 4] = make_float4(o0, o1, o2, o3);
    // final: logits[j] = sum_k M[j][k]*o[k] + bf[j]; redundant per group
    const int j = lane & 15;
    const float* orow = oL[wv];
    float a0 = 0.f, a1 = 0.f, a2 = 0.f, a3 = 0.f;
#pragma unroll
    for (int g = 0; g < 8; ++g) {
        float4 ov = *(const float4*)&orow[g * 4];
        float4 mv = *(const float4*)&Mp[g][j][0];
        a0 += ov.x * mv.x; a1 += ov.y * mv.y;
        a2 += ov.z * mv.z; a3 += ov.w * mv.w;
    }
    float logit = (a0 + a1) + (a2 + a3) + bfs[j];
    float mx = logit;
    mx = fmaxf(mx, __shfl_xor(mx, 1));
    mx = fmaxf(mx, __shfl_xor(mx, 2));
    mx = fmaxf(mx, __shfl_xor(mx, 4));
    mx = fmaxf(mx, __shfl_xor(mx, 8));
    float ex = __expf(logit - mx);
    float se = ex;
    se += __shfl_xor(se, 1);
    se += __shfl_xor(se, 2);
    se += __shfl_xor(se, 4);
    se += __shfl_xor(se, 8);
    float res = logit - (mx + __logf(se));
    if (lane < 16) out[(size_t)n * 16 + j] = res;
}

// ---------------- fold ----------------
__global__ __launch_bounds__(256) void fold_kernel(
    const float* __restrict__ in_proj_w, const float* __restrict__ in_proj_b,
    const float* __restrict__ out_proj_w, const float* __restrict__ out_proj_b,
    const float* __restrict__ fc_w, const float* __restrict__ fc_b,
    float* __restrict__ M, float* __restrict__ bf) {
    __shared__ float Wvo[32 * 32];
    __shared__ float bvo[32];
    const float* Wv = in_proj_w + 64 * 32;
    const float* bv = in_proj_b + 64;
    int t = threadIdx.x;
    for (int idx = t; idx < 1024; idx += 256) {
        int i = idx >> 5, j = idx & 31;
        float s = 0.f;
        for (int k = 0; k < 32; ++k) s += out_proj_w[i * 32 + k] * Wv[k * 32 + j];
        Wvo[idx] = s;
    }
    if (t < 32) {
        float s = 0.f;
        for (int k = 0; k < 32; ++k) s += out_proj_w[t * 32 + k] * bv[k];
        bvo[t] = s + out_proj_b[t];
    }
    __syncthreads();
    for (int idx = t; idx < 16 * 32; idx += 256) {
        int c = idx >> 5, j = idx & 31;
        float s = 0.f;
        for (int i = 0; i < 32; ++i) s += fc_w[c * 32 + i] * Wvo[i * 32 + j];
        M[idx] = s;
    }
    if (t < 16) {
        float s = 0.f;
        for (int i = 0; i < 32; ++i) s += fc_w[t * 32 + i] * bvo[i];
        bf[t] = s + fc_b[t];
    }
}

extern "C" void kernel_launch(void* const* d_in, const int* in_sizes, int n_in,
                              void* d_out, int out_size, void* d_ws, size_t ws_size,
                              hipStream_t stream) {
    const float* x   = (const float*)d_in[0];
    const int*   ei  = (const int*)d_in[1];
    const float* W1  = (const float*)d_in[2];
    const float* a1s = (const float*)d_in[3];
    const float* a1d = (const float*)d_in[4];
    const float* b1  = (const float*)d_in[5];
    const float* W2  = (const float*)d_in[6];
    const float* a2s = (const float*)d_in[7];
    const float* a2d = (const float*)d_in[8];
    const float* b2  = (const float*)d_in[9];
    const float* ipw = (const float*)d_in[10];
    const float* ipb = (const float*)d_in[11];
    const float* opw = (const float*)d_in[12];
    const float* opb = (const float*)d_in[13];
    const float* fcw = (const float*)d_in[14];
    const float* fcb = (const float*)d_in[15];
    float* out = (float*)d_out;

    int N = in_sizes[0] / 128;
    int E = in_sizes[1] / 2;
    int Et = E + N;
    int NB = (N + BMASK) >> BSHIFT;
    int NTILES = (Et + TILE - 1) / TILE;

    char* ws = (char*)d_ws;
    size_t off = 0;
    auto alloc = [&](size_t bytes) -> void* {
        void* p = ws + off;
        off += bytes;
        off = (off + 255) & ~(size_t)255;
        return p;
    };
    int*   bcount = (int*)alloc(MAXNB * 4);
    int*   bbase  = (int*)alloc(MAXNB * 4);
    int*   gcur   = (int*)alloc(MAXNB * 4);
    unsigned int*   rec  = (unsigned int*)alloc((size_t)Et * 4);
    int*   rowp   = (int*)alloc((size_t)(N + 1) * 4);
    unsigned short* esrc = (unsigned short*)alloc((size_t)Et * 2);
    __hip_bfloat16* h1 = (__hip_bfloat16*)alloc((size_t)N * 64 * 2);
    float* al1s  = (float*)alloc((size_t)N * 8 * 4);
    float* al1d  = (float*)alloc((size_t)N * 8 * 4);
    __hip_bfloat16* h2 = (__hip_bfloat16*)alloc((size_t)N * 32 * 2);
    float* al2s  = (float*)alloc((size_t)N * 8 * 4);
    float* al2d  = (float*)alloc((size_t)N * 8 * 4);
    float* Mf    = (float*)alloc(512 * 4);
    float* bff   = (float*)alloc(16 * 4);
    (void)ws_size; (void)n_in; (void)out_size;

    hipMemsetAsync(bcount, 0, MAXNB * 4, stream);
    bin_count_kernel<<<NTILES, 256, 0, stream>>>(ei, E, Et, NB, bcount);
    bucket_scan_kernel<<<1, 512, 0, stream>>>(bcount, bbase, gcur, NB);
    bin_scatter_kernel<<<NTILES, 256, 0, stream>>>(ei, E, Et, NB, gcur, rec);
    csr_finalize_kernel<<<NB, 256, 0, stream>>>(rec, bcount, bbase, rowp, esrc, N, Et);

    gemm1_mfma_kernel<<<(N + 63) / 64, 256, 0, stream>>>(x, W1, a1s, a1d, h1, al1s, al1d, N);
    fold_kernel<<<1, 256, 0, stream>>>(ipw, ipb, opw, opb, fcw, fcb, Mf, bff);
    gat_agg64_g2_kernel<<<(N + 3) / 4, 256, 0, stream>>>(
        rowp, esrc, h1, al1s, al1d, b1, W2, a2s, a2d, h2, al2s, al2d, N);
    gat_agg32_fin_kernel<<<(N + 3) / 4, 256, 0, stream>>>(
        rowp, esrc, h2, al2s, al2d, b2, Mf, bff, out, N);
}

// Round 14
// 255.691 us; speedup vs baseline: 1.0885x; 1.0885x over previous
//
#include <hip/hip_runtime.h>
#include <hip/hip_bf16.h>
#include <math.h>

// ---------------------------------------------------------------------------
// GAT x2 + folded (v-proj -> out-proj -> fc) + log_softmax
//   CSR build: bucket-binning (128-node buckets), esrc uint16, TILE=8192.
//   gemm1: MFMA bf16 16x16x32, 64x64 tile; h1 stored as PACKED FP8 e4m3
//     (3.2 MB table -> fits 4 MB per-XCD L2; kills agg64's 86 MB L2-miss
//     gather traffic). Attention logits stay fp32.
//   gat_agg64_g2: 1 node/wave, quad layout x4 + esrc prefetch, 4B fp8
//     gathers + v_cvt_f32_fp8 decode; fused gemm2 (R11 staging: write
//     conflicts cheaper than uncoalesced-read "fix", R12 lesson).
//   gat_agg32_fin: 1 node/wave, masked 4-stream loop; fused final.
//   Lessons: independent gather streams >> fewer VALU instrs (R6/R8);
//   __shfl = DS op, avoid in epilogues (R7); many short blocks >> few long
//   blocks (R10); don't trade LDS write conflicts for uncoalesced global (R12).
// ---------------------------------------------------------------------------

#define BSHIFT 7
#define BMASK  ((1 << BSHIFT) - 1)
#define MAXNB  512
#define TILE   8192
#define XST    136

typedef __attribute__((ext_vector_type(8))) short short8;
typedef __attribute__((ext_vector_type(4))) float floatx4;

__device__ __forceinline__ unsigned short f2bf(float f) {
    union { float f; unsigned int u; } v; v.f = f;
    unsigned int u = v.u;
    return (unsigned short)((u + 0x7FFFu + ((u >> 16) & 1u)) >> 16);  // RNE
}
__device__ __forceinline__ float bfl2f(unsigned int p) {
    return __uint_as_float(p << 16);
}
__device__ __forceinline__ float bfh2f(unsigned int p) {
    return __uint_as_float(p & 0xFFFF0000u);
}
__device__ __forceinline__ float lrelu(float e) { return fmaxf(e, 0.2f * e); }
__device__ __forceinline__ float elu(float o) {
    return (o > 0.f) ? o : (__expf(o) - 1.f);
}

// ---------------- CSR build (bucket binning) ----------------
__global__ __launch_bounds__(256) void bin_count_kernel(
    const int* __restrict__ ei, int E, int Et, int NB,
    int* __restrict__ bcount) {
    __shared__ int h[MAXNB];
    for (int i = threadIdx.x; i < NB; i += 256) h[i] = 0;
    __syncthreads();
    int tile0 = blockIdx.x * TILE;
    int jend = tile0 + TILE; if (jend > Et) jend = Et;
    for (int j = tile0 + threadIdx.x; j < jend; j += 256) {
        int d = (j < E) ? ei[E + j] : (j - E);
        atomicAdd(&h[d >> BSHIFT], 1);
    }
    __syncthreads();
    for (int i = threadIdx.x; i < NB; i += 256)
        if (h[i]) atomicAdd(&bcount[i], h[i]);
}

__global__ __launch_bounds__(512) void bucket_scan_kernel(
    const int* __restrict__ bcount, int* __restrict__ bbase,
    int* __restrict__ gcur, int NB) {
    __shared__ int s[512];
    int t = threadIdx.x;
    int v = (t < NB) ? bcount[t] : 0;
    s[t] = v;
    __syncthreads();
    for (int off = 1; off < 512; off <<= 1) {
        int u = (t >= off) ? s[t - off] : 0;
        __syncthreads();
        s[t] += u;
        __syncthreads();
    }
    if (t < NB) { int b = s[t] - v; bbase[t] = b; gcur[t] = b; }
}

__global__ __launch_bounds__(256) void bin_scatter_kernel(
    const int* __restrict__ ei, int E, int Et, int NB,
    int* __restrict__ gcur, unsigned int* __restrict__ rec) {
    __shared__ int h[MAXNB];
    __shared__ int cur[MAXNB];
    for (int i = threadIdx.x; i < NB; i += 256) h[i] = 0;
    __syncthreads();
    int tile0 = blockIdx.x * TILE;
    int jend = tile0 + TILE; if (jend > Et) jend = Et;
    for (int j = tile0 + threadIdx.x; j < jend; j += 256) {
        int d = (j < E) ? ei[E + j] : (j - E);
        atomicAdd(&h[d >> BSHIFT], 1);
    }
    __syncthreads();
    for (int i = threadIdx.x; i < NB; i += 256)
        cur[i] = atomicAdd(&gcur[i], h[i]);
    __syncthreads();
    for (int j = tile0 + threadIdx.x; j < jend; j += 256) {
        int srcv, d;
        if (j < E) { srcv = ei[j]; d = ei[E + j]; } else { srcv = j - E; d = j - E; }
        int b = d >> BSHIFT;
        int pos = atomicAdd(&cur[b], 1);
        rec[pos] = (unsigned)srcv | ((unsigned)(d & BMASK) << 16);
    }
}

__global__ __launch_bounds__(256) void csr_finalize_kernel(
    const unsigned int* __restrict__ rec, const int* __restrict__ bcount,
    const int* __restrict__ bbase, int* __restrict__ rowp,
    unsigned short* __restrict__ esrc, int N, int Et) {
    __shared__ int h[128];
    __shared__ int nb[128];
    __shared__ int cur[128];
    int b = blockIdx.x, t = threadIdx.x;
    int base = bbase[b], cnt = bcount[b];
    if (t < 128) h[t] = 0;
    __syncthreads();
    for (int i = t; i < cnt; i += 256)
        atomicAdd(&h[(rec[base + i] >> 16) & 127], 1);
    __syncthreads();
    if (t == 0) {
        int run = base;
        for (int i = 0; i < 128; ++i) { nb[i] = run; run += h[i]; }
    }
    __syncthreads();
    if (t < 128) cur[t] = nb[t];
    int n0 = b << BSHIFT;
    if (t < 128 && n0 + t < N) rowp[n0 + t] = nb[t];
    if (b == 0 && t == 0) rowp[N] = Et;
    __syncthreads();
    for (int i = t; i < cnt; i += 256) {
        unsigned r = rec[base + i];
        int pos = atomicAdd(&cur[(r >> 16) & 127], 1);
        esrc[pos] = (unsigned short)(r & 0xFFFFu);
    }
}

// ---------------- gemm1 via MFMA; h1 packed fp8 e4m3 ----------------
__global__ __launch_bounds__(256) void gemm1_mfma_kernel(
    const float* __restrict__ x, const float* __restrict__ W,
    const float* __restrict__ a_src, const float* __restrict__ a_dst,
    unsigned int* __restrict__ h1p, float* __restrict__ als,
    float* __restrict__ ald, int N) {
    __shared__ __align__(16) unsigned short xs[64 * XST];
    __shared__ __align__(16) unsigned short wt[64 * XST];
    int t = threadIdx.x;
    int nb = blockIdx.x * 64;
#pragma unroll
    for (int r = 0; r < 8; ++r) {
        int p = t + 256 * r;
        int row = p >> 5;
        int c4  = p & 31;
        int n = nb + row;
        float4 v = (n < N) ? ((const float4*)x)[(size_t)n * 32 + c4]
                           : make_float4(0.f, 0.f, 0.f, 0.f);
        unsigned short* dst = &xs[row * XST + c4 * 4];
        dst[0] = f2bf(v.x); dst[1] = f2bf(v.y);
        dst[2] = f2bf(v.z); dst[3] = f2bf(v.w);
    }
    {
        int n = t & 63, kg = t >> 6;
#pragma unroll
        for (int c = 0; c < 4; ++c) {
            int k0 = kg * 32 + c * 8;
            unsigned short* dst = &wt[n * XST + k0];
#pragma unroll
            for (int j = 0; j < 8; ++j)
                dst[j] = f2bf(W[(k0 + j) * 64 + n]);
        }
    }
    __syncthreads();
    int wave = t >> 6, lane = t & 63;
    int m16 = lane & 15, quad = lane >> 4;
    floatx4 acc[4];
#pragma unroll
    for (int i = 0; i < 4; ++i) acc[i] = (floatx4){0.f, 0.f, 0.f, 0.f};
#pragma unroll
    for (int k = 0; k < 4; ++k) {
        int koff = k * 32 + quad * 8;
        short8 afrag = *(const short8*)&xs[(wave * 16 + m16) * XST + koff];
#pragma unroll
        for (int nt = 0; nt < 4; ++nt) {
            short8 bfrag = *(const short8*)&wt[(nt * 16 + m16) * XST + koff];
            acc[nt] = __builtin_amdgcn_mfma_f32_16x16x32_bf16(afrag, bfrag, acc[nt], 0, 0, 0);
        }
    }
    __syncthreads();
    float* hs = (float*)xs;                // [64][65]
#pragma unroll
    for (int nt = 0; nt < 4; ++nt)
#pragma unroll
        for (int r = 0; r < 4; ++r)
            hs[(wave * 16 + quad * 4 + r) * 65 + nt * 16 + m16] = acc[nt][r];
    __syncthreads();
    float asv = a_src[lane], adv = a_dst[lane];
    for (int itn = 0; itn < 16; ++itn) {
        int nl = wave * 16 + itn;
        int n = nb + nl;
        if (n >= N) break;
        float v = hs[nl * 65 + lane];
        float ps = v * asv, pd = v * adv;
        ps += __shfl_xor(ps, 1); ps += __shfl_xor(ps, 2); ps += __shfl_xor(ps, 4);
        pd += __shfl_xor(pd, 1); pd += __shfl_xor(pd, 2); pd += __shfl_xor(pd, 4);
        if ((lane & 7) == 0) {
            als[n * 8 + (lane >> 3)] = ps;
            ald[n * 8 + (lane >> 3)] = pd;
        }
        if (lane < 16) {                  // pack 4 channels -> fp8x4
            const float* hr = &hs[nl * 65 + lane * 4];
            int pk = __builtin_amdgcn_cvt_pk_fp8_f32(hr[0], hr[1], 0, false);
            pk = __builtin_amdgcn_cvt_pk_fp8_f32(hr[2], hr[3], pk, true);
            h1p[(size_t)n * 16 + lane] = (unsigned)pk;
        }
    }
}

// ---------------- agg layer 1 (quad x4 + prefetch, fp8 feat) + gemm2 ------
// One wave per node (4 nodes/block). 4B fp8x4 gathers; table L2-resident.
__global__ __launch_bounds__(256) void gat_agg64_g2_kernel(
    const int* __restrict__ rowp, const unsigned short* __restrict__ esrc,
    const unsigned int* __restrict__ feat, const float* __restrict__ als,
    const float* __restrict__ ald_arr, const float* __restrict__ bias,
    const float* __restrict__ W2, const float* __restrict__ a2s,
    const float* __restrict__ a2d,
    __hip_bfloat16* __restrict__ h2out, float* __restrict__ als2,
    float* __restrict__ ald2, int N) {
    __shared__ __align__(16) float W2p[2][8][32][4];  // [kh][g][l][jj]
    __shared__ __align__(16) float oL[4][64];
    int t = threadIdx.x;
    for (int idx = t; idx < 2048; idx += 256) {
        int k = idx >> 5, l = idx & 31;
        W2p[k >> 5][(k & 31) >> 2][l][k & 3] = W2[idx];
    }
    __syncthreads();
    const int lane = t & 63;
    const int wv = t >> 6;
    const int e = lane >> 4;             // edge slot 0..3
    const int c = lane & 15;             // channel quad
    const int hd = c >> 1;               // head
    int n = blockIdx.x * 4 + wv;
    if (n >= N) return;
    float aldv = ald_arr[n * 8 + hd];
    int beg = rowp[n], end = rowp[n + 1];
    float dA = 0.f, dB = 0.f;
    float p00 = 0.f, p01 = 0.f, p02 = 0.f, p03 = 0.f;
    float p10 = 0.f, p11 = 0.f, p12 = 0.f, p13 = 0.f;
    float p20 = 0.f, p21 = 0.f, p22 = 0.f, p23 = 0.f;
    float p30 = 0.f, p31 = 0.f, p32 = 0.f, p33 = 0.f;
    int i = beg;
    int s0, s1, s2, s3;
    bool has = (i + 16 <= end);
    if (has) {
        s0 = esrc[i + e]; s1 = esrc[i + 4 + e];
        s2 = esrc[i + 8 + e]; s3 = esrc[i + 12 + e];
    }
    while (has) {
        int t0 = s0, t1 = s1, t2 = s2, t3 = s3;
        i += 16;
        has = (i + 16 <= end);
        if (has) {                        // prefetch next group
            s0 = esrc[i + e]; s1 = esrc[i + 4 + e];
            s2 = esrc[i + 8 + e]; s3 = esrc[i + 12 + e];
        }
        float e0 = als[t0 * 8 + hd] + aldv;
        float e1 = als[t1 * 8 + hd] + aldv;
        float e2 = als[t2 * 8 + hd] + aldv;
        float e3 = als[t3 * 8 + hd] + aldv;
        unsigned g0 = feat[t0 * 16 + c];
        unsigned g1 = feat[t1 * 16 + c];
        unsigned g2 = feat[t2 * 16 + c];
        unsigned g3 = feat[t3 * 16 + c];
        float w0 = __expf(lrelu(e0));
        float w1 = __expf(lrelu(e1));
        float w2 = __expf(lrelu(e2));
        float w3 = __expf(lrelu(e3));
        dA += w0; dB += w1; dA += w2; dB += w3;
        p00 += w0 * __builtin_amdgcn_cvt_f32_fp8(g0, 0);
        p01 += w0 * __builtin_amdgcn_cvt_f32_fp8(g0, 1);
        p02 += w0 * __builtin_amdgcn_cvt_f32_fp8(g0, 2);
        p03 += w0 * __builtin_amdgcn_cvt_f32_fp8(g0, 3);
        p10 += w1 * __builtin_amdgcn_cvt_f32_fp8(g1, 0);
        p11 += w1 * __builtin_amdgcn_cvt_f32_fp8(g1, 1);
        p12 += w1 * __builtin_amdgcn_cvt_f32_fp8(g1, 2);
        p13 += w1 * __builtin_amdgcn_cvt_f32_fp8(g1, 3);
        p20 += w2 * __builtin_amdgcn_cvt_f32_fp8(g2, 0);
        p21 += w2 * __builtin_amdgcn_cvt_f32_fp8(g2, 1);
        p22 += w2 * __builtin_amdgcn_cvt_f32_fp8(g2, 2);
        p23 += w2 * __builtin_amdgcn_cvt_f32_fp8(g2, 3);
        p30 += w3 * __builtin_amdgcn_cvt_f32_fp8(g3, 0);
        p31 += w3 * __builtin_amdgcn_cvt_f32_fp8(g3, 1);
        p32 += w3 * __builtin_amdgcn_cvt_f32_fp8(g3, 2);
        p33 += w3 * __builtin_amdgcn_cvt_f32_fp8(g3, 3);
    }
    for (; i < end; i += 4) {            // masked tail, 4 at a time
        int rem = end - i;
        int ee = (e < rem) ? e : rem - 1;
        int s = esrc[i + ee];
        float ev = als[s * 8 + hd] + aldv;
        unsigned g = feat[s * 16 + c];
        float w = (e < rem) ? __expf(lrelu(ev)) : 0.f;
        dA += w;
        p00 += w * __builtin_amdgcn_cvt_f32_fp8(g, 0);
        p01 += w * __builtin_amdgcn_cvt_f32_fp8(g, 1);
        p02 += w * __builtin_amdgcn_cvt_f32_fp8(g, 2);
        p03 += w * __builtin_amdgcn_cvt_f32_fp8(g, 3);
    }
    float d = dA + dB;
    float P0 = (p00 + p10) + (p20 + p30);
    float P1 = (p01 + p11) + (p21 + p31);
    float P2 = (p02 + p12) + (p22 + p32);
    float P3 = (p03 + p13) + (p23 + p33);
    d  += __shfl_xor(d, 16);  d  += __shfl_xor(d, 32);
    P0 += __shfl_xor(P0, 16); P0 += __shfl_xor(P0, 32);
    P1 += __shfl_xor(P1, 16); P1 += __shfl_xor(P1, 32);
    P2 += __shfl_xor(P2, 16); P2 += __shfl_xor(P2, 32);
    P3 += __shfl_xor(P3, 16); P3 += __shfl_xor(P3, 32);
    float inv = 1.f / (d + 1e-16f);
    float4 bv = ((const float4*)bias)[c];
    float o0 = elu(P0 * inv + bv.x);
    float o1 = elu(P1 * inv + bv.y);
    float o2 = elu(P2 * inv + bv.z);
    float o3 = elu(P3 * inv + bv.w);
    if (lane < 16) *(float4*)&oL[wv][c * 4] = make_float4(o0, o1, o2, o3);
    // gemm2: h2[l] = sum_k o[k]*W2[k][l]; split-k over wave halves
    const int l = lane & 31, kh = lane >> 5;
    const float* orow = &oL[wv][kh * 32];
    float a0 = 0.f, a1 = 0.f, a2 = 0.f, a3 = 0.f;
#pragma unroll
    for (int g = 0; g < 8; ++g) {
        float4 ov = *(const float4*)&orow[g * 4];
        float4 wv4 = *(const float4*)&W2p[kh][g][l][0];
        a0 += ov.x * wv4.x; a1 += ov.y * wv4.y;
        a2 += ov.z * wv4.z; a3 += ov.w * wv4.w;
    }
    float acc = (a0 + a1) + (a2 + a3);
    acc += __shfl_xor(acc, 32);
    float ps = acc * a2s[l], pd = acc * a2d[l];
    ps += __shfl_xor(ps, 1); ps += __shfl_xor(ps, 2);
    pd += __shfl_xor(pd, 1); pd += __shfl_xor(pd, 2);
    if (lane < 32) {
        h2out[(size_t)n * 32 + l] = __float2bfloat16(acc);
        if ((l & 3) == 0) {
            als2[n * 8 + (l >> 2)] = ps;
            ald2[n * 8 + (l >> 2)] = pd;
        }
    }
}

// ---------------- agg layer 2 (octo, masked 4-stream) + fused final -------
__global__ __launch_bounds__(256) void gat_agg32_fin_kernel(
    const int* __restrict__ rowp, const unsigned short* __restrict__ esrc,
    const __hip_bfloat16* __restrict__ feat, const float* __restrict__ als,
    const float* __restrict__ ald_arr, const float* __restrict__ bias,
    const float* __restrict__ M, const float* __restrict__ bf,
    float* __restrict__ out, int N) {
    __shared__ __align__(16) float Mp[8][16][4];   // [g][j][jj]
    __shared__ float bfs[16];
    __shared__ __align__(16) float oL[4][32];
    int t = threadIdx.x;
    for (int i = t; i < 512; i += 256) {
        int j = i >> 5, k = i & 31;
        Mp[k >> 2][j][k & 3] = M[i];
    }
    if (t < 16) bfs[t] = bf[t];
    __syncthreads();
    const int lane = t & 63;
    const int wv = t >> 6;
    const int e = lane >> 3;             // edge slot 0..7
    const int c = lane & 7;              // head, channels 4c..4c+3
    int n = blockIdx.x * 4 + wv;
    if (n >= N) return;
    float aldv = ald_arr[n * 8 + c];
    int beg = rowp[n], end = rowp[n + 1];
    float d0 = 0.f, d1 = 0.f, d2 = 0.f, d3 = 0.f;
    float p00 = 0.f, p01 = 0.f, p02 = 0.f, p03 = 0.f;
    float p10 = 0.f, p11 = 0.f, p12 = 0.f, p13 = 0.f;
    float p20 = 0.f, p21 = 0.f, p22 = 0.f, p23 = 0.f;
    float p30 = 0.f, p31 = 0.f, p32 = 0.f, p33 = 0.f;
    const uint2* fp = (const uint2*)feat;    // 8 granules per row
    for (int base = beg; base < end; base += 32) {
        int i0 = base + e;
        int i1 = base + 8 + e;
        int i2 = base + 16 + e;
        int i3 = base + 24 + e;
        bool v0 = i0 < end, v1 = i1 < end, v2 = i2 < end, v3 = i3 < end;
        int c0 = v0 ? i0 : beg;
        int c1 = v1 ? i1 : beg;
        int c2 = v2 ? i2 : beg;
        int c3 = v3 ? i3 : beg;
        int s0 = esrc[c0], s1 = esrc[c1], s2 = esrc[c2], s3 = esrc[c3];
        float e0 = als[s0 * 8 + c] + aldv;
        float e1 = als[s1 * 8 + c] + aldv;
        float e2 = als[s2 * 8 + c] + aldv;
        float e3 = als[s3 * 8 + c] + aldv;
        uint2 g0 = fp[s0 * 8 + c];
        uint2 g1 = fp[s1 * 8 + c];
        uint2 g2 = fp[s2 * 8 + c];
        uint2 g3 = fp[s3 * 8 + c];
        float w0 = v0 ? __expf(lrelu(e0)) : 0.f;
        float w1 = v1 ? __expf(lrelu(e1)) : 0.f;
        float w2 = v2 ? __expf(lrelu(e2)) : 0.f;
        float w3 = v3 ? __expf(lrelu(e3)) : 0.f;
        d0 += w0; d1 += w1; d2 += w2; d3 += w3;
        p00 += w0 * bfl2f(g0.x); p01 += w0 * bfh2f(g0.x);
        p02 += w0 * bfl2f(g0.y); p03 += w0 * bfh2f(g0.y);
        p10 += w1 * bfl2f(g1.x); p11 += w1 * bfh2f(g1.x);
        p12 += w1 * bfl2f(g1.y); p13 += w1 * bfh2f(g1.y);
        p20 += w2 * bfl2f(g2.x); p21 += w2 * bfh2f(g2.x);
        p22 += w2 * bfl2f(g2.y); p23 += w2 * bfh2f(g2.y);
        p30 += w3 * bfl2f(g3.x); p31 += w3 * bfh2f(g3.x);
        p32 += w3 * bfl2f(g3.y); p33 += w3 * bfh2f(g3.y);
    }
    float d = (d0 + d1) + (d2 + d3);
    float P0 = (p00 + p10) + (p20 + p30);
    float P1 = (p01 + p11) + (p21 + p31);
    float P2 = (p02 + p12) + (p22 + p32);
    float P3 = (p03 + p13) + (p23 + p33);
    d  += __shfl_xor(d, 8);  d  += __shfl_xor(d, 16);  d  += __shfl_xor(d, 32);
    P0 += __shfl_xor(P0, 8); P0 += __shfl_xor(P0, 16); P0 += __shfl_xor(P0, 32);
    P1 += __shfl_xor(P1, 8); P1 += __shfl_xor(P1, 16); P1 += __shfl_xor(P1, 32);
    P2 += __shfl_xor(P2, 8); P2 += __shfl_xor(P2, 16); P2 += __shfl_xor(P2, 32);
    P3 += __shfl_xor(P3, 8); P3 += __shfl_xor(P3, 16); P3 += __shfl_xor(P3, 32);
    float inv = 1.f / (d + 1e-16f);
    float4 bv = ((const float4*)bias)[c];
    float o0 = elu(P0 * inv + bv.x);
    float o1 = elu(P1 * inv + bv.y);
    float o2 = elu(P2 * inv + bv.z);
    float o3 = elu(P3 * inv + bv.w);
    if (lane < 8) *(float4*)&oL[wv][c * 4] = make_float4(o0, o1, o2, o3);
    // final: logits[j] = sum_k M[j][k]*o[k] + bf[j]; redundant per group
    const int j = lane & 15;
    const float* orow = oL[wv];
    float a0 = 0.f, a1 = 0.f, a2 = 0.f, a3 = 0.f;
#pragma unroll
    for (int g = 0; g < 8; ++g) {
        float4 ov = *(const float4*)&orow[g * 4];
        float4 mv = *(const float4*)&Mp[g][j][0];
        a0 += ov.x * mv.x; a1 += ov.y * mv.y;
        a2 += ov.z * mv.z; a3 += ov.w * mv.w;
    }
    float logit = (a0 + a1) + (a2 + a3) + bfs[j];
    float mx = logit;
    mx = fmaxf(mx, __shfl_xor(mx, 1));
    mx = fmaxf(mx, __shfl_xor(mx, 2));
    mx = fmaxf(mx, __shfl_xor(mx, 4));
    mx = fmaxf(mx, __shfl_xor(mx, 8));
    float ex = __expf(logit - mx);
    float se = ex;
    se += __shfl_xor(se, 1);
    se += __shfl_xor(se, 2);
    se += __shfl_xor(se, 4);
    se += __shfl_xor(se, 8);
    float res = logit - (mx + __logf(se));
    if (lane < 16) out[(size_t)n * 16 + j] = res;
}

// ---------------- fold ----------------
__global__ __launch_bounds__(256) void fold_kernel(
    const float* __restrict__ in_proj_w, const float* __restrict__ in_proj_b,
    const float* __restrict__ out_proj_w, const float* __restrict__ out_proj_b,
    const float* __restrict__ fc_w, const float* __restrict__ fc_b,
    float* __restrict__ M, float* __restrict__ bf) {
    __shared__ float Wvo[32 * 32];
    __shared__ float bvo[32];
    const float* Wv = in_proj_w + 64 * 32;
    const float* bv = in_proj_b + 64;
    int t = threadIdx.x;
    for (int idx = t; idx < 1024; idx += 256) {
        int i = idx >> 5, j = idx & 31;
        float s = 0.f;
        for (int k = 0; k < 32; ++k) s += out_proj_w[i * 32 + k] * Wv[k * 32 + j];
        Wvo[idx] = s;
    }
    if (t < 32) {
        float s = 0.f;
        for (int k = 0; k < 32; ++k) s += out_proj_w[t * 32 + k] * bv[k];
        bvo[t] = s + out_proj_b[t];
    }
    __syncthreads();
    for (int idx = t; idx < 16 * 32; idx += 256) {
        int c = idx >> 5, j = idx & 31;
        float s = 0.f;
        for (int i = 0; i < 32; ++i) s += fc_w[c * 32 + i] * Wvo[i * 32 + j];
        M[idx] = s;
    }
    if (t < 16) {
        float s = 0.f;
        for (int i = 0; i < 32; ++i) s += fc_w[t * 32 + i] * bvo[i];
        bf[t] = s + fc_b[t];
    }
}

extern "C" void kernel_launch(void* const* d_in, const int* in_sizes, int n_in,
                              void* d_out, int out_size, void* d_ws, size_t ws_size,
                              hipStream_t stream) {
    const float* x   = (const float*)d_in[0];
    const int*   ei  = (const int*)d_in[1];
    const float* W1  = (const float*)d_in[2];
    const float* a1s = (const float*)d_in[3];
    const float* a1d = (const float*)d_in[4];
    const float* b1  = (const float*)d_in[5];
    const float* W2  = (const float*)d_in[6];
    const float* a2s = (const float*)d_in[7];
    const float* a2d = (const float*)d_in[8];
    const float* b2  = (const float*)d_in[9];
    const float* ipw = (const float*)d_in[10];
    const float* ipb = (const float*)d_in[11];
    const float* opw = (const float*)d_in[12];
    const float* opb = (const float*)d_in[13];
    const float* fcw = (const float*)d_in[14];
    const float* fcb = (const float*)d_in[15];
    float* out = (float*)d_out;

    int N = in_sizes[0] / 128;
    int E = in_sizes[1] / 2;
    int Et = E + N;
    int NB = (N + BMASK) >> BSHIFT;
    int NTILES = (Et + TILE - 1) / TILE;

    char* ws = (char*)d_ws;
    size_t off = 0;
    auto alloc = [&](size_t bytes) -> void* {
        void* p = ws + off;
        off += bytes;
        off = (off + 255) & ~(size_t)255;
        return p;
    };
    int*   bcount = (int*)alloc(MAXNB * 4);
    int*   bbase  = (int*)alloc(MAXNB * 4);
    int*   gcur   = (int*)alloc(MAXNB * 4);
    unsigned int*   rec  = (unsigned int*)alloc((size_t)Et * 4);
    int*   rowp   = (int*)alloc((size_t)(N + 1) * 4);
    unsigned short* esrc = (unsigned short*)alloc((size_t)Et * 2);
    unsigned int* h1p = (unsigned int*)alloc((size_t)N * 16 * 4);  // fp8x4
    float* al1s  = (float*)alloc((size_t)N * 8 * 4);
    float* al1d  = (float*)alloc((size_t)N * 8 * 4);
    __hip_bfloat16* h2 = (__hip_bfloat16*)alloc((size_t)N * 32 * 2);
    float* al2s  = (float*)alloc((size_t)N * 8 * 4);
    float* al2d  = (float*)alloc((size_t)N * 8 * 4);
    float* Mf    = (float*)alloc(512 * 4);
    float* bff   = (float*)alloc(16 * 4);
    (void)ws_size; (void)n_in; (void)out_size;

    hipMemsetAsync(bcount, 0, MAXNB * 4, stream);
    bin_count_kernel<<<NTILES, 256, 0, stream>>>(ei, E, Et, NB, bcount);
    bucket_scan_kernel<<<1, 512, 0, stream>>>(bcount, bbase, gcur, NB);
    bin_scatter_kernel<<<NTILES, 256, 0, stream>>>(ei, E, Et, NB, gcur, rec);
    csr_finalize_kernel<<<NB, 256, 0, stream>>>(rec, bcount, bbase, rowp, esrc, N, Et);

    gemm1_mfma_kernel<<<(N + 63) / 64, 256, 0, stream>>>(x, W1, a1s, a1d, h1p, al1s, al1d, N);
    fold_kernel<<<1, 256, 0, stream>>>(ipw, ipb, opw, opb, fcw, fcb, Mf, bff);
    gat_agg64_g2_kernel<<<(N + 3) / 4, 256, 0, stream>>>(
        rowp, esrc, h1p, al1s, al1d, b1, W2, a2s, a2d, h2, al2s, al2d, N);
    gat_agg32_fin_kernel<<<(N + 3) / 4, 256, 0, stream>>>(
        rowp, esrc, h2, al2s, al2d, b2, Mf, bff, out, N);
}

// Round 15
// 249.655 us; speedup vs baseline: 1.1149x; 1.0242x over previous
//
#include <hip/hip_runtime.h>
#include <hip/hip_bf16.h>
#include <math.h>

// ---------------------------------------------------------------------------
// GAT x2 + folded (v-proj -> out-proj -> fc) + log_softmax
//   CSR build: bucket-binning (128-node buckets), esrc uint16, TILE=8192.
//   gemm1: MFMA bf16; h1 stored PACKED FP8 e4m3 (3.2 MB, L2-resident -- R13
//     win: FETCH 86->48 MB). h2 ALSO fp8 (1.6 MB) this round.
//   gat_agg64_g2 / gat_agg32_fin: VALU-bound now (71%) -> packed decode
//     (v_cvt_pk_f32_fp8) + float2 accumulate (v_pk_fma_f32): ~2x fewer
//     decode/FMA instrs per edge.
//   Lessons: independent gather streams >> fewer VALU instrs when latency-
//   bound (R6/R8) -- but now VALU-bound, so packed math pays; __shfl = DS op
//   (R7); many short blocks >> few long (R10); L2-resident gather tables (R13).
// ---------------------------------------------------------------------------

#define BSHIFT 7
#define BMASK  ((1 << BSHIFT) - 1)
#define MAXNB  512
#define TILE   8192
#define XST    136

typedef __attribute__((ext_vector_type(8))) short short8;
typedef __attribute__((ext_vector_type(4))) float floatx4;
typedef __attribute__((ext_vector_type(2))) float floatx2;

__device__ __forceinline__ unsigned short f2bf(float f) {
    union { float f; unsigned int u; } v; v.f = f;
    unsigned int u = v.u;
    return (unsigned short)((u + 0x7FFFu + ((u >> 16) & 1u)) >> 16);  // RNE
}
__device__ __forceinline__ float lrelu(float e) { return fmaxf(e, 0.2f * e); }
__device__ __forceinline__ float elu(float o) {
    return (o > 0.f) ? o : (__expf(o) - 1.f);
}

// ---------------- CSR build (bucket binning) ----------------
__global__ __launch_bounds__(256) void bin_count_kernel(
    const int* __restrict__ ei, int E, int Et, int NB,
    int* __restrict__ bcount) {
    __shared__ int h[MAXNB];
    for (int i = threadIdx.x; i < NB; i += 256) h[i] = 0;
    __syncthreads();
    int tile0 = blockIdx.x * TILE;
    int jend = tile0 + TILE; if (jend > Et) jend = Et;
    for (int j = tile0 + threadIdx.x; j < jend; j += 256) {
        int d = (j < E) ? ei[E + j] : (j - E);
        atomicAdd(&h[d >> BSHIFT], 1);
    }
    __syncthreads();
    for (int i = threadIdx.x; i < NB; i += 256)
        if (h[i]) atomicAdd(&bcount[i], h[i]);
}

__global__ __launch_bounds__(512) void bucket_scan_kernel(
    const int* __restrict__ bcount, int* __restrict__ bbase,
    int* __restrict__ gcur, int NB) {
    __shared__ int s[512];
    int t = threadIdx.x;
    int v = (t < NB) ? bcount[t] : 0;
    s[t] = v;
    __syncthreads();
    for (int off = 1; off < 512; off <<= 1) {
        int u = (t >= off) ? s[t - off] : 0;
        __syncthreads();
        s[t] += u;
        __syncthreads();
    }
    if (t < NB) { int b = s[t] - v; bbase[t] = b; gcur[t] = b; }
}

__global__ __launch_bounds__(256) void bin_scatter_kernel(
    const int* __restrict__ ei, int E, int Et, int NB,
    int* __restrict__ gcur, unsigned int* __restrict__ rec) {
    __shared__ int h[MAXNB];
    __shared__ int cur[MAXNB];
    for (int i = threadIdx.x; i < NB; i += 256) h[i] = 0;
    __syncthreads();
    int tile0 = blockIdx.x * TILE;
    int jend = tile0 + TILE; if (jend > Et) jend = Et;
    for (int j = tile0 + threadIdx.x; j < jend; j += 256) {
        int d = (j < E) ? ei[E + j] : (j - E);
        atomicAdd(&h[d >> BSHIFT], 1);
    }
    __syncthreads();
    for (int i = threadIdx.x; i < NB; i += 256)
        cur[i] = atomicAdd(&gcur[i], h[i]);
    __syncthreads();
    for (int j = tile0 + threadIdx.x; j < jend; j += 256) {
        int srcv, d;
        if (j < E) { srcv = ei[j]; d = ei[E + j]; } else { srcv = j - E; d = j - E; }
        int b = d >> BSHIFT;
        int pos = atomicAdd(&cur[b], 1);
        rec[pos] = (unsigned)srcv | ((unsigned)(d & BMASK) << 16);
    }
}

__global__ __launch_bounds__(256) void csr_finalize_kernel(
    const unsigned int* __restrict__ rec, const int* __restrict__ bcount,
    const int* __restrict__ bbase, int* __restrict__ rowp,
    unsigned short* __restrict__ esrc, int N, int Et) {
    __shared__ int h[128];
    __shared__ int nb[128];
    __shared__ int cur[128];
    int b = blockIdx.x, t = threadIdx.x;
    int base = bbase[b], cnt = bcount[b];
    if (t < 128) h[t] = 0;
    __syncthreads();
    for (int i = t; i < cnt; i += 256)
        atomicAdd(&h[(rec[base + i] >> 16) & 127], 1);
    __syncthreads();
    if (t == 0) {
        int run = base;
        for (int i = 0; i < 128; ++i) { nb[i] = run; run += h[i]; }
    }
    __syncthreads();
    if (t < 128) cur[t] = nb[t];
    int n0 = b << BSHIFT;
    if (t < 128 && n0 + t < N) rowp[n0 + t] = nb[t];
    if (b == 0 && t == 0) rowp[N] = Et;
    __syncthreads();
    for (int i = t; i < cnt; i += 256) {
        unsigned r = rec[base + i];
        int pos = atomicAdd(&cur[(r >> 16) & 127], 1);
        esrc[pos] = (unsigned short)(r & 0xFFFFu);
    }
}

// ---------------- gemm1 via MFMA; h1 packed fp8 e4m3 ----------------
__global__ __launch_bounds__(256) void gemm1_mfma_kernel(
    const float* __restrict__ x, const float* __restrict__ W,
    const float* __restrict__ a_src, const float* __restrict__ a_dst,
    unsigned int* __restrict__ h1p, float* __restrict__ als,
    float* __restrict__ ald, int N) {
    __shared__ __align__(16) unsigned short xs[64 * XST];
    __shared__ __align__(16) unsigned short wt[64 * XST];
    int t = threadIdx.x;
    int nb = blockIdx.x * 64;
#pragma unroll
    for (int r = 0; r < 8; ++r) {
        int p = t + 256 * r;
        int row = p >> 5;
        int c4  = p & 31;
        int n = nb + row;
        float4 v = (n < N) ? ((const float4*)x)[(size_t)n * 32 + c4]
                           : make_float4(0.f, 0.f, 0.f, 0.f);
        unsigned short* dst = &xs[row * XST + c4 * 4];
        dst[0] = f2bf(v.x); dst[1] = f2bf(v.y);
        dst[2] = f2bf(v.z); dst[3] = f2bf(v.w);
    }
    {
        int n = t & 63, kg = t >> 6;
#pragma unroll
        for (int c = 0; c < 4; ++c) {
            int k0 = kg * 32 + c * 8;
            unsigned short* dst = &wt[n * XST + k0];
#pragma unroll
            for (int j = 0; j < 8; ++j)
                dst[j] = f2bf(W[(k0 + j) * 64 + n]);
        }
    }
    __syncthreads();
    int wave = t >> 6, lane = t & 63;
    int m16 = lane & 15, quad = lane >> 4;
    floatx4 acc[4];
#pragma unroll
    for (int i = 0; i < 4; ++i) acc[i] = (floatx4){0.f, 0.f, 0.f, 0.f};
#pragma unroll
    for (int k = 0; k < 4; ++k) {
        int koff = k * 32 + quad * 8;
        short8 afrag = *(const short8*)&xs[(wave * 16 + m16) * XST + koff];
#pragma unroll
        for (int nt = 0; nt < 4; ++nt) {
            short8 bfrag = *(const short8*)&wt[(nt * 16 + m16) * XST + koff];
            acc[nt] = __builtin_amdgcn_mfma_f32_16x16x32_bf16(afrag, bfrag, acc[nt], 0, 0, 0);
        }
    }
    __syncthreads();
    float* hs = (float*)xs;                // [64][65]
#pragma unroll
    for (int nt = 0; nt < 4; ++nt)
#pragma unroll
        for (int r = 0; r < 4; ++r)
            hs[(wave * 16 + quad * 4 + r) * 65 + nt * 16 + m16] = acc[nt][r];
    __syncthreads();
    float asv = a_src[lane], adv = a_dst[lane];
    for (int itn = 0; itn < 16; ++itn) {
        int nl = wave * 16 + itn;
        int n = nb + nl;
        if (n >= N) break;
        float v = hs[nl * 65 + lane];
        float ps = v * asv, pd = v * adv;
        ps += __shfl_xor(ps, 1); ps += __shfl_xor(ps, 2); ps += __shfl_xor(ps, 4);
        pd += __shfl_xor(pd, 1); pd += __shfl_xor(pd, 2); pd += __shfl_xor(pd, 4);
        if ((lane & 7) == 0) {
            als[n * 8 + (lane >> 3)] = ps;
            ald[n * 8 + (lane >> 3)] = pd;
        }
        if (lane < 16) {                  // pack 4 channels -> fp8x4
            const float* hr = &hs[nl * 65 + lane * 4];
            int pk = __builtin_amdgcn_cvt_pk_fp8_f32(hr[0], hr[1], 0, false);
            pk = __builtin_amdgcn_cvt_pk_fp8_f32(hr[2], hr[3], pk, true);
            h1p[(size_t)n * 16 + lane] = (unsigned)pk;
        }
    }
}

// ---------------- agg layer 1 (quad x4, fp8 pk decode) + fused gemm2 ------
// One wave per node (4 nodes/block). 4B fp8x4 gathers; packed cvt + pk fma.
// Epilogue writes h2 as fp8 (via intra-wave LDS bounce) + al2s/al2d.
__global__ __launch_bounds__(256) void gat_agg64_g2_kernel(
    const int* __restrict__ rowp, const unsigned short* __restrict__ esrc,
    const unsigned int* __restrict__ feat, const float* __restrict__ als,
    const float* __restrict__ ald_arr, const float* __restrict__ bias,
    const float* __restrict__ W2, const float* __restrict__ a2s,
    const float* __restrict__ a2d,
    unsigned int* __restrict__ h2p, float* __restrict__ als2,
    float* __restrict__ ald2, int N) {
    __shared__ __align__(16) float W2p[2][8][32][4];  // [kh][g][l][jj]
    __shared__ __align__(16) float oL[4][64];
    __shared__ __align__(16) float h2L[4][32];
    int t = threadIdx.x;
    for (int idx = t; idx < 2048; idx += 256) {
        int k = idx >> 5, l = idx & 31;
        W2p[k >> 5][(k & 31) >> 2][l][k & 3] = W2[idx];
    }
    __syncthreads();
    const int lane = t & 63;
    const int wv = t >> 6;
    const int e = lane >> 4;             // edge slot 0..3
    const int c = lane & 15;             // channel quad
    const int hd = c >> 1;               // head
    int n = blockIdx.x * 4 + wv;
    if (n >= N) return;
    float aldv = ald_arr[n * 8 + hd];
    int beg = rowp[n], end = rowp[n + 1];
    float dA = 0.f, dB = 0.f;
    floatx2 p0a = {0.f, 0.f}, p0b = {0.f, 0.f};
    floatx2 p1a = {0.f, 0.f}, p1b = {0.f, 0.f};
    floatx2 p2a = {0.f, 0.f}, p2b = {0.f, 0.f};
    floatx2 p3a = {0.f, 0.f}, p3b = {0.f, 0.f};
    int i = beg;
    int s0, s1, s2, s3;
    bool has = (i + 16 <= end);
    if (has) {
        s0 = esrc[i + e]; s1 = esrc[i + 4 + e];
        s2 = esrc[i + 8 + e]; s3 = esrc[i + 12 + e];
    }
    while (has) {
        int t0 = s0, t1 = s1, t2 = s2, t3 = s3;
        i += 16;
        has = (i + 16 <= end);
        if (has) {                        // prefetch next group
            s0 = esrc[i + e]; s1 = esrc[i + 4 + e];
            s2 = esrc[i + 8 + e]; s3 = esrc[i + 12 + e];
        }
        float e0 = als[t0 * 8 + hd] + aldv;
        float e1 = als[t1 * 8 + hd] + aldv;
        float e2 = als[t2 * 8 + hd] + aldv;
        float e3 = als[t3 * 8 + hd] + aldv;
        unsigned g0 = feat[t0 * 16 + c];
        unsigned g1 = feat[t1 * 16 + c];
        unsigned g2 = feat[t2 * 16 + c];
        unsigned g3 = feat[t3 * 16 + c];
        float w0 = __expf(lrelu(e0));
        float w1 = __expf(lrelu(e1));
        float w2 = __expf(lrelu(e2));
        float w3 = __expf(lrelu(e3));
        dA += w0; dB += w1; dA += w2; dB += w3;
        p0a += w0 * __builtin_amdgcn_cvt_pk_f32_fp8(g0, false);
        p0b += w0 * __builtin_amdgcn_cvt_pk_f32_fp8(g0, true);
        p1a += w1 * __builtin_amdgcn_cvt_pk_f32_fp8(g1, false);
        p1b += w1 * __builtin_amdgcn_cvt_pk_f32_fp8(g1, true);
        p2a += w2 * __builtin_amdgcn_cvt_pk_f32_fp8(g2, false);
        p2b += w2 * __builtin_amdgcn_cvt_pk_f32_fp8(g2, true);
        p3a += w3 * __builtin_amdgcn_cvt_pk_f32_fp8(g3, false);
        p3b += w3 * __builtin_amdgcn_cvt_pk_f32_fp8(g3, true);
    }
    for (; i < end; i += 4) {            // masked tail, 4 at a time
        int rem = end - i;
        int ee = (e < rem) ? e : rem - 1;
        int s = esrc[i + ee];
        float ev = als[s * 8 + hd] + aldv;
        unsigned g = feat[s * 16 + c];
        float w = (e < rem) ? __expf(lrelu(ev)) : 0.f;
        dA += w;
        p0a += w * __builtin_amdgcn_cvt_pk_f32_fp8(g, false);
        p0b += w * __builtin_amdgcn_cvt_pk_f32_fp8(g, true);
    }
    float d = dA + dB;
    floatx2 Pa = (p0a + p1a) + (p2a + p3a);
    floatx2 Pb = (p0b + p1b) + (p2b + p3b);
    float P0 = Pa.x, P1 = Pa.y, P2 = Pb.x, P3 = Pb.y;
    d  += __shfl_xor(d, 16);  d  += __shfl_xor(d, 32);
    P0 += __shfl_xor(P0, 16); P0 += __shfl_xor(P0, 32);
    P1 += __shfl_xor(P1, 16); P1 += __shfl_xor(P1, 32);
    P2 += __shfl_xor(P2, 16); P2 += __shfl_xor(P2, 32);
    P3 += __shfl_xor(P3, 16); P3 += __shfl_xor(P3, 32);
    float inv = 1.f / (d + 1e-16f);
    float4 bv = ((const float4*)bias)[c];
    float o0 = elu(P0 * inv + bv.x);
    float o1 = elu(P1 * inv + bv.y);
    float o2 = elu(P2 * inv + bv.z);
    float o3 = elu(P3 * inv + bv.w);
    if (lane < 16) *(float4*)&oL[wv][c * 4] = make_float4(o0, o1, o2, o3);
    // gemm2: h2[l] = sum_k o[k]*W2[k][l]; split-k over wave halves
    const int l = lane & 31, kh = lane >> 5;
    const float* orow = &oL[wv][kh * 32];
    float a0 = 0.f, a1 = 0.f, a2 = 0.f, a3 = 0.f;
#pragma unroll
    for (int g = 0; g < 8; ++g) {
        float4 ov = *(const float4*)&orow[g * 4];
        float4 wv4 = *(const float4*)&W2p[kh][g][l][0];
        a0 += ov.x * wv4.x; a1 += ov.y * wv4.y;
        a2 += ov.z * wv4.z; a3 += ov.w * wv4.w;
    }
    float acc = (a0 + a1) + (a2 + a3);
    acc += __shfl_xor(acc, 32);
    float ps = acc * a2s[l], pd = acc * a2d[l];
    ps += __shfl_xor(ps, 1); ps += __shfl_xor(ps, 2);
    pd += __shfl_xor(pd, 1); pd += __shfl_xor(pd, 2);
    if (lane < 32) {
        h2L[wv][l] = acc;                 // intra-wave LDS bounce for packing
        if ((l & 3) == 0) {
            als2[n * 8 + (l >> 2)] = ps;
            ald2[n * 8 + (l >> 2)] = pd;
        }
    }
    if (lane < 8) {                       // pack 4 channels -> fp8x4
        const float* hr = &h2L[wv][lane * 4];
        int pk = __builtin_amdgcn_cvt_pk_fp8_f32(hr[0], hr[1], 0, false);
        pk = __builtin_amdgcn_cvt_pk_fp8_f32(hr[2], hr[3], pk, true);
        h2p[(size_t)n * 8 + lane] = (unsigned)pk;
    }
}

// ---------------- agg layer 2 (octo, fp8 pk decode) + fused final ---------
// One wave per node (4 nodes/block). lane = e*8 + c; 4B fp8x4 gathers.
__global__ __launch_bounds__(256) void gat_agg32_fin_kernel(
    const int* __restrict__ rowp, const unsigned short* __restrict__ esrc,
    const unsigned int* __restrict__ feat, const float* __restrict__ als,
    const float* __restrict__ ald_arr, const float* __restrict__ bias,
    const float* __restrict__ M, const float* __restrict__ bf,
    float* __restrict__ out, int N) {
    __shared__ __align__(16) float Mp[8][16][4];   // [g][j][jj]
    __shared__ float bfs[16];
    __shared__ __align__(16) float oL[4][32];
    int t = threadIdx.x;
    for (int i = t; i < 512; i += 256) {
        int j = i >> 5, k = i & 31;
        Mp[k >> 2][j][k & 3] = M[i];
    }
    if (t < 16) bfs[t] = bf[t];
    __syncthreads();
    const int lane = t & 63;
    const int wv = t >> 6;
    const int e = lane >> 3;             // edge slot 0..7
    const int c = lane & 7;              // head, channels 4c..4c+3
    int n = blockIdx.x * 4 + wv;
    if (n >= N) return;
    float aldv = ald_arr[n * 8 + c];
    int beg = rowp[n], end = rowp[n + 1];
    float d0 = 0.f, d1 = 0.f, d2 = 0.f, d3 = 0.f;
    floatx2 p0a = {0.f, 0.f}, p0b = {0.f, 0.f};
    floatx2 p1a = {0.f, 0.f}, p1b = {0.f, 0.f};
    floatx2 p2a = {0.f, 0.f}, p2b = {0.f, 0.f};
    floatx2 p3a = {0.f, 0.f}, p3b = {0.f, 0.f};
    for (int base = beg; base < end; base += 32) {
        int i0 = base + e;
        int i1 = base + 8 + e;
        int i2 = base + 16 + e;
        int i3 = base + 24 + e;
        bool v0 = i0 < end, v1 = i1 < end, v2 = i2 < end, v3 = i3 < end;
        int c0 = v0 ? i0 : beg;
        int c1 = v1 ? i1 : beg;
        int c2 = v2 ? i2 : beg;
        int c3 = v3 ? i3 : beg;
        int s0 = esrc[c0], s1 = esrc[c1], s2 = esrc[c2], s3 = esrc[c3];
        float e0 = als[s0 * 8 + c] + aldv;
        float e1 = als[s1 * 8 + c] + aldv;
        float e2 = als[s2 * 8 + c] + aldv;
        float e3 = als[s3 * 8 + c] + aldv;
        unsigned g0 = feat[s0 * 8 + c];
        unsigned g1 = feat[s1 * 8 + c];
        unsigned g2 = feat[s2 * 8 + c];
        unsigned g3 = feat[s3 * 8 + c];
        float w0 = v0 ? __expf(lrelu(e0)) : 0.f;
        float w1 = v1 ? __expf(lrelu(e1)) : 0.f;
        float w2 = v2 ? __expf(lrelu(e2)) : 0.f;
        float w3 = v3 ? __expf(lrelu(e3)) : 0.f;
        d0 += w0; d1 += w1; d2 += w2; d3 += w3;
        p0a += w0 * __builtin_amdgcn_cvt_pk_f32_fp8(g0, false);
        p0b += w0 * __builtin_amdgcn_cvt_pk_f32_fp8(g0, true);
        p1a += w1 * __builtin_amdgcn_cvt_pk_f32_fp8(g1, false);
        p1b += w1 * __builtin_amdgcn_cvt_pk_f32_fp8(g1, true);
        p2a += w2 * __builtin_amdgcn_cvt_pk_f32_fp8(g2, false);
        p2b += w2 * __builtin_amdgcn_cvt_pk_f32_fp8(g2, true);
        p3a += w3 * __builtin_amdgcn_cvt_pk_f32_fp8(g3, false);
        p3b += w3 * __builtin_amdgcn_cvt_pk_f32_fp8(g3, true);
    }
    float d = (d0 + d1) + (d2 + d3);
    floatx2 Pa = (p0a + p1a) + (p2a + p3a);
    floatx2 Pb = (p0b + p1b) + (p2b + p3b);
    float P0 = Pa.x, P1 = Pa.y, P2 = Pb.x, P3 = Pb.y;
    d  += __shfl_xor(d, 8);  d  += __shfl_xor(d, 16);  d  += __shfl_xor(d, 32);
    P0 += __shfl_xor(P0, 8); P0 += __shfl_xor(P0, 16); P0 += __shfl_xor(P0, 32);
    P1 += __shfl_xor(P1, 8); P1 += __shfl_xor(P1, 16); P1 += __shfl_xor(P1, 32);
    P2 += __shfl_xor(P2, 8); P2 += __shfl_xor(P2, 16); P2 += __shfl_xor(P2, 32);
    P3 += __shfl_xor(P3, 8); P3 += __shfl_xor(P3, 16); P3 += __shfl_xor(P3, 32);
    float inv = 1.f / (d + 1e-16f);
    float4 bv = ((const float4*)bias)[c];
    float o0 = elu(P0 * inv + bv.x);
    float o1 = elu(P1 * inv + bv.y);
    float o2 = elu(P2 * inv + bv.z);
    float o3 = elu(P3 * inv + bv.w);
    if (lane < 8) *(float4*)&oL[wv][c * 4] = make_float4(o0, o1, o2, o3);
    // final: logits[j] = sum_k M[j][k]*o[k] + bf[j]; redundant per group
    const int j = lane & 15;
    const float* orow = oL[wv];
    float a0 = 0.f, a1 = 0.f, a2 = 0.f, a3 = 0.f;
#pragma unroll
    for (int g = 0; g < 8; ++g) {
        float4 ov = *(const float4*)&orow[g * 4];
        float4 mv = *(const float4*)&Mp[g][j][0];
        a0 += ov.x * mv.x; a1 += ov.y * mv.y;
        a2 += ov.z * mv.z; a3 += ov.w * mv.w;
    }
    float logit = (a0 + a1) + (a2 + a3) + bfs[j];
    float mx = logit;
    mx = fmaxf(mx, __shfl_xor(mx, 1));
    mx = fmaxf(mx, __shfl_xor(mx, 2));
    mx = fmaxf(mx, __shfl_xor(mx, 4));
    mx = fmaxf(mx, __shfl_xor(mx, 8));
    float ex = __expf(logit - mx);
    float se = ex;
    se += __shfl_xor(se, 1);
    se += __shfl_xor(se, 2);
    se += __shfl_xor(se, 4);
    se += __shfl_xor(se, 8);
    float res = logit - (mx + __logf(se));
    if (lane < 16) out[(size_t)n * 16 + j] = res;
}

// ---------------- fold ----------------
__global__ __launch_bounds__(256) void fold_kernel(
    const float* __restrict__ in_proj_w, const float* __restrict__ in_proj_b,
    const float* __restrict__ out_proj_w, const float* __restrict__ out_proj_b,
    const float* __restrict__ fc_w, const float* __restrict__ fc_b,
    float* __restrict__ M, float* __restrict__ bf) {
    __shared__ float Wvo[32 * 32];
    __shared__ float bvo[32];
    const float* Wv = in_proj_w + 64 * 32;
    const float* bv = in_proj_b + 64;
    int t = threadIdx.x;
    for (int idx = t; idx < 1024; idx += 256) {
        int i = idx >> 5, j = idx & 31;
        float s = 0.f;
        for (int k = 0; k < 32; ++k) s += out_proj_w[i * 32 + k] * Wv[k * 32 + j];
        Wvo[idx] = s;
    }
    if (t < 32) {
        float s = 0.f;
        for (int k = 0; k < 32; ++k) s += out_proj_w[t * 32 + k] * bv[k];
        bvo[t] = s + out_proj_b[t];
    }
    __syncthreads();
    for (int idx = t; idx < 16 * 32; idx += 256) {
        int c = idx >> 5, j = idx & 31;
        float s = 0.f;
        for (int i = 0; i < 32; ++i) s += fc_w[c * 32 + i] * Wvo[i * 32 + j];
        M[idx] = s;
    }
    if (t < 16) {
        float s = 0.f;
        for (int i = 0; i < 32; ++i) s += fc_w[t * 32 + i] * bvo[i];
        bf[t] = s + fc_b[t];
    }
}

extern "C" void kernel_launch(void* const* d_in, const int* in_sizes, int n_in,
                              void* d_out, int out_size, void* d_ws, size_t ws_size,
                              hipStream_t stream) {
    const float* x   = (const float*)d_in[0];
    const int*   ei  = (const int*)d_in[1];
    const float* W1  = (const float*)d_in[2];
    const float* a1s = (const float*)d_in[3];
    const float* a1d = (const float*)d_in[4];
    const float* b1  = (const float*)d_in[5];
    const float* W2  = (const float*)d_in[6];
    const float* a2s = (const float*)d_in[7];
    const float* a2d = (const float*)d_in[8];
    const float* b2  = (const float*)d_in[9];
    const float* ipw = (const float*)d_in[10];
    const float* ipb = (const float*)d_in[11];
    const float* opw = (const float*)d_in[12];
    const float* opb = (const float*)d_in[13];
    const float* fcw = (const float*)d_in[14];
    const float* fcb = (const float*)d_in[15];
    float* out = (float*)d_out;

    int N = in_sizes[0] / 128;
    int E = in_sizes[1] / 2;
    int Et = E + N;
    int NB = (N + BMASK) >> BSHIFT;
    int NTILES = (Et + TILE - 1) / TILE;

    char* ws = (char*)d_ws;
    size_t off = 0;
    auto alloc = [&](size_t bytes) -> void* {
        void* p = ws + off;
        off += bytes;
        off = (off + 255) & ~(size_t)255;
        return p;
    };
    int*   bcount = (int*)alloc(MAXNB * 4);
    int*   bbase  = (int*)alloc(MAXNB * 4);
    int*   gcur   = (int*)alloc(MAXNB * 4);
    unsigned int*   rec  = (unsigned int*)alloc((size_t)Et * 4);
    int*   rowp   = (int*)alloc((size_t)(N + 1) * 4);
    unsigned short* esrc = (unsigned short*)alloc((size_t)Et * 2);
    unsigned int* h1p = (unsigned int*)alloc((size_t)N * 16 * 4);  // fp8x4
    float* al1s  = (float*)alloc((size_t)N * 8 * 4);
    float* al1d  = (float*)alloc((size_t)N * 8 * 4);
    unsigned int* h2p = (unsigned int*)alloc((size_t)N * 8 * 4);   // fp8x4
    float* al2s  = (float*)alloc((size_t)N * 8 * 4);
    float* al2d  = (float*)alloc((size_t)N * 8 * 4);
    float* Mf    = (float*)alloc(512 * 4);
    float* bff   = (float*)alloc(16 * 4);
    (void)ws_size; (void)n_in; (void)out_size;

    hipMemsetAsync(bcount, 0, MAXNB * 4, stream);
    bin_count_kernel<<<NTILES, 256, 0, stream>>>(ei, E, Et, NB, bcount);
    bucket_scan_kernel<<<1, 512, 0, stream>>>(bcount, bbase, gcur, NB);
    bin_scatter_kernel<<<NTILES, 256, 0, stream>>>(ei, E, Et, NB, gcur, rec);
    csr_finalize_kernel<<<NB, 256, 0, stream>>>(rec, bcount, bbase, rowp, esrc, N, Et);

    gemm1_mfma_kernel<<<(N + 63) / 64, 256, 0, stream>>>(x, W1, a1s, a1d, h1p, al1s, al1d, N);
    fold_kernel<<<1, 256, 0, stream>>>(ipw, ipb, opw, opb, fcw, fcb, Mf, bff);
    gat_agg64_g2_kernel<<<(N + 3) / 4, 256, 0, stream>>>(
        rowp, esrc, h1p, al1s, al1d, b1, W2, a2s, a2d, h2p, al2s, al2d, N);
    gat_agg32_fin_kernel<<<(N + 3) / 4, 256, 0, stream>>>(
        rowp, esrc, h2p, al2s, al2d, b2, Mf, bff, out, N);
}